// Round 12
// baseline (988.663 us; speedup 1.0000x reference)
//
#include <hip/hip_runtime.h>
#include <hip/hip_bf16.h>
#include <stdint.h>

#define B_  4
#define T_  2048
#define C_  2048
#define H_  32
#define S_  64
#define M_  (B_ * T_)     // 8192 rows
#define C4_ (4 * C_)      // 8192
#define C2_ (2 * C_)      // 4096
#define LN_EPS 1e-5f
#define NCH 16            // scan chunks
#define CLEN 128          // chunk length (NCH*CLEN == T_)
#define NCHAN (B_ * C_)   // 8192 scan channels

typedef unsigned short u16;
typedef __attribute__((ext_vector_type(8))) short short8;
typedef __attribute__((ext_vector_type(4))) float f32x4;

__device__ __forceinline__ u16 f2bf(float f) {
  uint32_t u = __float_as_uint(f);
  u = (u + 0x7FFFu + ((u >> 16) & 1u)) >> 16;
  return (u16)u;
}
__device__ __forceinline__ float bf2f(u16 u) {
  return __uint_as_float(((uint32_t)u) << 16);
}

__device__ __forceinline__ void gload_lds16(const void* g, void* l) {
  __builtin_amdgcn_global_load_lds(
      (const __attribute__((address_space(1))) uint32_t*)g,
      (__attribute__((address_space(3))) uint32_t*)l, 16, 0, 0);
}

// ---- transpose + cast: f32 in[R][Cn] (leading dim ld) -> bf16 out[Cn][R] ----
__global__ __launch_bounds__(256) void k_transpose_cast(
    const float* __restrict__ in, u16* __restrict__ out, int ld, int R, int Cn) {
  __shared__ float tile[32][33];
  const int tx = threadIdx.x & 31, ty = threadIdx.x >> 5; // ty 0..7
  const int c0 = blockIdx.x * 32, r0 = blockIdx.y * 32;
#pragma unroll
  for (int i = 0; i < 4; ++i) {
    int r = ty + i * 8;
    tile[r][tx] = in[(size_t)(r0 + r) * ld + (c0 + tx)];
  }
  __syncthreads();
#pragma unroll
  for (int i = 0; i < 4; ++i) {
    int cc = ty + i * 8;
    out[(size_t)(c0 + cc) * R + (r0 + tx)] = f2bf(tile[tx][cc]);
  }
}

// ---- z-batched chunk transpose: in = in0 + z*in_zoff, out = out0 + z*out_zoff ----
__global__ __launch_bounds__(256) void k_transpose_castZ(
    const float* __restrict__ in0, size_t in_zoff,
    u16* __restrict__ out0, size_t out_zoff, int ld, int R, int Cn) {
  __shared__ float tile[32][33];
  const float* in = in0 + in_zoff * blockIdx.z;
  u16* out = out0 + out_zoff * blockIdx.z;
  const int tx = threadIdx.x & 31, ty = threadIdx.x >> 5;
  const int c0 = blockIdx.x * 32, r0 = blockIdx.y * 32;
#pragma unroll
  for (int i = 0; i < 4; ++i) {
    int r = ty + i * 8;
    tile[r][tx] = in[(size_t)(r0 + r) * ld + (c0 + tx)];
  }
  __syncthreads();
#pragma unroll
  for (int i = 0; i < 4; ++i) {
    int cc = ty + i * 8;
    out[(size_t)(c0 + cc) * R + (r0 + tx)] = f2bf(tile[tx][cc]);
  }
}

// ---- batched square transpose: z selects one of 4 C_xC_ weights -> wbuf slice z ----
__global__ __launch_bounds__(256) void k_transpose_cast4(
    const float* __restrict__ w0, const float* __restrict__ w1,
    const float* __restrict__ w2, const float* __restrict__ w3,
    u16* __restrict__ out) {
  __shared__ float tile[32][33];
  const float* in = blockIdx.z == 0 ? w0 : blockIdx.z == 1 ? w1
                  : blockIdx.z == 2 ? w2 : w3;
  u16* o = out + (size_t)blockIdx.z * C_ * C_;
  const int tx = threadIdx.x & 31, ty = threadIdx.x >> 5;
  const int c0 = blockIdx.x * 32, r0 = blockIdx.y * 32;
#pragma unroll
  for (int i = 0; i < 4; ++i) {
    int r = ty + i * 8;
    tile[r][tx] = in[(size_t)(r0 + r) * C_ + (c0 + tx)];
  }
  __syncthreads();
#pragma unroll
  for (int i = 0; i < 4; ++i) {
    int cc = ty + i * 8;
    o[(size_t)(c0 + cc) * C_ + (r0 + tx)] = f2bf(tile[tx][cc]);
  }
}

// ---------------- LayerNorm f32 -> bf16, one block per row ----------------
__global__ __launch_bounds__(256) void k_layernorm_bf16(
    const float* __restrict__ x, const float* __restrict__ w,
    const float* __restrict__ bias, u16* __restrict__ out) {
  const int row = blockIdx.x;
  const int t = threadIdx.x;
  const float* xr = x + (size_t)row * C_;
  float4 a = ((const float4*)xr)[2 * t];
  float4 b = ((const float4*)xr)[2 * t + 1];
  float s = a.x + a.y + a.z + a.w + b.x + b.y + b.z + b.w;
  float q = a.x * a.x + a.y * a.y + a.z * a.z + a.w * a.w +
            b.x * b.x + b.y * b.y + b.z * b.z + b.w * b.w;
#pragma unroll
  for (int off = 32; off > 0; off >>= 1) {
    s += __shfl_down(s, off);
    q += __shfl_down(q, off);
  }
  __shared__ float rs[8];
  const int wv = t >> 6;
  if ((t & 63) == 0) { rs[wv] = s; rs[4 + wv] = q; }
  __syncthreads();
  s = rs[0] + rs[1] + rs[2] + rs[3];
  q = rs[4] + rs[5] + rs[6] + rs[7];
  const float mean = s * (1.0f / C_);
  const float rstd = rsqrtf(q * (1.0f / C_) - mean * mean + LN_EPS);
  float4 w0 = ((const float4*)w)[2 * t], w1 = ((const float4*)w)[2 * t + 1];
  float4 b0 = ((const float4*)bias)[2 * t], b1 = ((const float4*)bias)[2 * t + 1];
  uint4 pk;
  pk.x = (uint32_t)f2bf((a.x - mean) * rstd * w0.x + b0.x) |
         ((uint32_t)f2bf((a.y - mean) * rstd * w0.y + b0.y) << 16);
  pk.y = (uint32_t)f2bf((a.z - mean) * rstd * w0.z + b0.z) |
         ((uint32_t)f2bf((a.w - mean) * rstd * w0.w + b0.w) << 16);
  pk.z = (uint32_t)f2bf((b.x - mean) * rstd * w1.x + b1.x) |
         ((uint32_t)f2bf((b.y - mean) * rstd * w1.y + b1.y) << 16);
  pk.w = (uint32_t)f2bf((b.z - mean) * rstd * w1.z + b1.z) |
         ((uint32_t)f2bf((b.w - mean) * rstd * w1.w + b1.w) << 16);
  ((uint4*)(out + (size_t)row * C_))[t] = pk;
}

// ====== GEMM 256x256, BK=64, 8 waves, sparse barriers + counted vmcnt (R5, proven) ======
// SPLIT mode: A and B are each two half-K [rows][K/2] buffers (A1/A2, B1/B2);
// staging selects by kcol (wave-uniform; K/2 % 32 == 0 so each 32-col stage
// window lies entirely in one half). ds_read/MFMA side unchanged.
__device__ __forceinline__ void stage_half(
    const u16* __restrict__ G, int ldK, int row0, int kcol0,
    u16* lds_half, int tid) {
#pragma unroll
  for (int i = 0; i < 2; ++i) {
    const int slot = i * 512 + tid;
    const int row = slot >> 2;
    const int gs = slot & 3;
    const int gsrc = gs ^ ((row >> 1) & 3);
    gload_lds16(G + (size_t)(row0 + row) * ldK + kcol0 + gsrc * 8,
                ((char*)lds_half) + i * 8192 + (tid >> 6) * 1024);
  }
}

__device__ __forceinline__ short8 frag(const u16* half_base, int row, int g0) {
  const int g = g0 ^ ((row >> 1) & 3);
  return *(const short8*)(half_base + row * 32 + g * 8);
}

template <bool SPLIT, typename ACC>
__device__ __forceinline__ void gemm_body(
    const u16* __restrict__ A1, const u16* __restrict__ A2,
    const u16* __restrict__ B1, const u16* __restrict__ B2,
    int K, int bm0, int bn0, int tid, ACC& acc,
    u16 (*As)[2][256 * 32], u16 (*Bs)[2][256 * 32]) {
  const int wv = tid >> 6, ln = tid & 63;
  const int wm = wv >> 2, wn = wv & 3;
  const int l15 = ln & 15, g0 = ln >> 4;
  const int NT = K >> 6;
  const int Ksp = K >> 1;

  auto stageA = [&](int kcol, u16* dst) {
    if constexpr (SPLIT) {
      if (kcol < Ksp) stage_half(A1, Ksp, bm0, kcol, dst, tid);
      else            stage_half(A2, Ksp, bm0, kcol - Ksp, dst, tid);
    } else {
      stage_half(A1, K, bm0, kcol, dst, tid);
    }
  };
  auto stageB = [&](int kcol, u16* dst) {
    if constexpr (SPLIT) {
      if (kcol < Ksp) stage_half(B1, Ksp, bn0, kcol, dst, tid);
      else            stage_half(B2, Ksp, bn0, kcol - Ksp, dst, tid);
    } else {
      stage_half(B1, K, bn0, kcol, dst, tid);
    }
  };

  stageA(0, &As[0][0][0]);
  stageB(0, &Bs[0][0][0]);
  stageA(32, &As[0][1][0]);
  stageB(32, &Bs[0][1][0]);
  asm volatile("s_waitcnt vmcnt(4)" ::: "memory");
  __builtin_amdgcn_s_barrier();
  __builtin_amdgcn_sched_barrier(0);

  for (int t = 0; t < NT; ++t) {
    const int c = t & 1, nb = c ^ 1;
    const int kn = (t + 1) << 6;
    const bool stage_on = (t + 1 < NT);
    const bool lastt = (t + 1 == NT);
    short8 bfr[4], af[4];

#pragma unroll
    for (int h = 0; h < 2; ++h) {
#pragma unroll
      for (int n = 0; n < 4; ++n)
        bfr[n] = frag(&Bs[c][h][0], wn * 64 + n * 16 + l15, g0);
#pragma unroll
      for (int m = 0; m < 4; ++m)
        af[m] = frag(&As[c][h][0], wm * 128 + m * 16 + l15, g0);
      if (stage_on) stageA(kn + h * 32, &As[nb][h][0]);
#pragma unroll
      for (int m = 0; m < 4; ++m)
#pragma unroll
        for (int n = 0; n < 4; ++n)
          acc[m][n] = __builtin_amdgcn_mfma_f32_16x16x32_bf16(af[m], bfr[n], acc[m][n], 0, 0, 0);

#pragma unroll
      for (int m = 0; m < 4; ++m)
        af[m] = frag(&As[c][h][0], wm * 128 + 64 + m * 16 + l15, g0);
      if (stage_on) stageB(kn + h * 32, &Bs[nb][h][0]);
#pragma unroll
      for (int m = 0; m < 4; ++m)
#pragma unroll
        for (int n = 0; n < 4; ++n)
          acc[4 + m][n] = __builtin_amdgcn_mfma_f32_16x16x32_bf16(af[m], bfr[n], acc[4 + m][n], 0, 0, 0);

      if (h == 0) {
        if (!lastt) asm volatile("s_waitcnt vmcnt(4)" ::: "memory");  // t.K1 landed
        else        asm volatile("s_waitcnt vmcnt(0)" ::: "memory");
        __builtin_amdgcn_s_barrier();
        __builtin_amdgcn_sched_barrier(0);
      } else if (!lastt) {
        asm volatile("s_waitcnt vmcnt(4)" ::: "memory");              // (t+1).K0 landed
        __builtin_amdgcn_s_barrier();
        __builtin_amdgcn_sched_barrier(0);
      }
    }
  }
}

// XCD-aware remap (T1): bijective since nwg % 8 == 0 for all grids here.
__device__ __forceinline__ void xcd_remap(int& bm0, int& bn0) {
  const int lin = blockIdx.y * gridDim.x + blockIdx.x;
  const int xcd = lin & 7, slot = lin >> 3;
  const int bx = slot % gridDim.x;
  const int by = xcd * (gridDim.y >> 3) + slot / gridDim.x;
  bm0 = by * 256; bn0 = bx * 256;
}

// EPI: 0 f32 | 1 f32 Res+v | 2 bf16 | 3 bf16 relu^2 | 4 f32 +=
template <int EPI, bool SPLIT>
__global__ __launch_bounds__(512, 2) void k_gemm8(
    const u16* __restrict__ A1, const u16* __restrict__ A2,
    const u16* __restrict__ B1, const u16* __restrict__ B2,
    void* __restrict__ Out, const float* __restrict__ Res,
    int M, int N, int K) {
  __shared__ u16 As[2][2][256 * 32];
  __shared__ u16 Bs[2][2][256 * 32];
  const int tid = threadIdx.x;
  const int wv = tid >> 6, ln = tid & 63;
  const int wm = wv >> 2, wn = wv & 3;
  const int l15 = ln & 15;
  int bm0, bn0;
  xcd_remap(bm0, bn0);

  f32x4 acc[8][4];
#pragma unroll
  for (int m = 0; m < 8; ++m)
#pragma unroll
    for (int n = 0; n < 4; ++n) acc[m][n] = (f32x4)0.0f;

  gemm_body<SPLIT>(A1, A2, B1, B2, K, bm0, bn0, tid, acc, As, Bs);

#pragma unroll
  for (int m = 0; m < 8; ++m) {
    const int r_base = bm0 + wm * 128 + m * 16 + (ln >> 4) * 4;
#pragma unroll
    for (int n = 0; n < 4; ++n) {
      const int cidx = bn0 + wn * 64 + n * 16 + l15;
#pragma unroll
      for (int i = 0; i < 4; ++i) {
        const size_t off = (size_t)(r_base + i) * N + cidx;
        const float v = acc[m][n][i];
        if constexpr (EPI == 0) {
          ((float*)Out)[off] = v;
        } else if constexpr (EPI == 1) {
          ((float*)Out)[off] = Res[off] + v;
        } else if constexpr (EPI == 2) {
          ((u16*)Out)[off] = f2bf(v);
        } else if constexpr (EPI == 3) {
          const float tpos = v > 0.0f ? v : 0.0f;
          ((u16*)Out)[off] = f2bf(tpos * tpos);
        } else {
          ((float*)Out)[off] += v;
        }
      }
    }
  }
}

// k/v/r fused: z selects weight slice (Wt + z*C*C) and output buffer; bf16 out.
__global__ __launch_bounds__(512, 2) void k_gemm8_kvr(
    const u16* __restrict__ A, const u16* __restrict__ Wt,
    u16* __restrict__ kb, u16* __restrict__ vb, u16* __restrict__ rb) {
  __shared__ u16 As[2][2][256 * 32];
  __shared__ u16 Bs[2][2][256 * 32];
  const int tid = threadIdx.x;
  const int wv = tid >> 6, ln = tid & 63;
  const int wm = wv >> 2, wn = wv & 3;
  const int l15 = ln & 15;
  const u16* Bt = Wt + (size_t)blockIdx.z * C_ * C_;
  u16* Out = blockIdx.z == 0 ? kb : blockIdx.z == 1 ? vb : rb;
  int bm0, bn0;
  xcd_remap(bm0, bn0);

  f32x4 acc[8][4];
#pragma unroll
  for (int m = 0; m < 8; ++m)
#pragma unroll
    for (int n = 0; n < 4; ++n) acc[m][n] = (f32x4)0.0f;

  gemm_body<false>(A, nullptr, Bt, nullptr, C_, bm0, bn0, tid, acc, As, Bs);

#pragma unroll
  for (int m = 0; m < 8; ++m) {
    const int r_base = bm0 + wm * 128 + m * 16 + (ln >> 4) * 4;
#pragma unroll
    for (int n = 0; n < 4; ++n) {
      const int cidx = bn0 + wn * 64 + n * 16 + l15;
#pragma unroll
      for (int i = 0; i < 4; ++i)
        Out[(size_t)(r_base + i) * C_ + cidx] = f2bf(acc[m][n][i]);
    }
  }
}

// z=4 shared-A FFN-Wfk GEMM: hidden chunk z = relu(xl2 @ WfkT_z)^2 -> o[z].
// A shared across z -> staging A-panels hit XCD-L2 for z>=1 (kvr mechanism,
// measured 45.7% MfmaUtil vs 38% solo in R11).
__global__ __launch_bounds__(512, 2) void k_gemm8_ffk4(
    const u16* __restrict__ A, const u16* __restrict__ Wt,
    u16* __restrict__ o0, u16* __restrict__ o1,
    u16* __restrict__ o2, u16* __restrict__ o3) {
  __shared__ u16 As[2][2][256 * 32];
  __shared__ u16 Bs[2][2][256 * 32];
  const int tid = threadIdx.x;
  const int wv = tid >> 6, ln = tid & 63;
  const int wm = wv >> 2, wn = wv & 3;
  const int l15 = ln & 15;
  const u16* Bt = Wt + (size_t)blockIdx.z * C_ * C_;
  u16* Out = blockIdx.z == 0 ? o0 : blockIdx.z == 1 ? o1
           : blockIdx.z == 2 ? o2 : o3;
  int bm0, bn0;
  xcd_remap(bm0, bn0);

  f32x4 acc[8][4];
#pragma unroll
  for (int m = 0; m < 8; ++m)
#pragma unroll
    for (int n = 0; n < 4; ++n) acc[m][n] = (f32x4)0.0f;

  gemm_body<false>(A, nullptr, Bt, nullptr, C_, bm0, bn0, tid, acc, As, Bs);

#pragma unroll
  for (int m = 0; m < 8; ++m) {
    const int r_base = bm0 + wm * 128 + m * 16 + (ln >> 4) * 4;
#pragma unroll
    for (int n = 0; n < 4; ++n) {
      const int cidx = bn0 + wn * 64 + n * 16 + l15;
#pragma unroll
      for (int i = 0; i < 4; ++i) {
        const float v = acc[m][n][i];
        const float tpos = v > 0.0f ? v : 0.0f;
        Out[(size_t)(r_base + i) * C_ + cidx] = f2bf(tpos * tpos);
      }
    }
  }
}

// ---------------- wkv scan, 3 passes (chunked exp-decay cumsum) ----------------
__global__ __launch_bounds__(256) void k_scan_a(
    const u16* __restrict__ kk, const u16* __restrict__ vv,
    const float* __restrict__ td, float* __restrict__ Sloc) {
  const int g = blockIdx.x * 256 + threadIdx.x;
  const int j = blockIdx.y;
  const int ch = g & (C_ - 1);
  const float d = __expf(-__expf(td[ch]));
  const size_t base = ((size_t)(g >> 11) * T_ + (size_t)j * CLEN) * C_ + ch;
  float s = 0.0f;
#pragma unroll 4
  for (int t = 0; t < CLEN; ++t) {
    const size_t idx = base + (size_t)t * C_;
    s = d * s + __expf(bf2f(kk[idx])) * bf2f(vv[idx]);
  }
  Sloc[(size_t)j * NCHAN + g] = s;
}

__global__ __launch_bounds__(256) void k_scan_b(
    const float* __restrict__ td, const float* __restrict__ Sloc,
    float* __restrict__ carry) {
  const int g = blockIdx.x * 256 + threadIdx.x;
  const int ch = g & (C_ - 1);
  const float dL = __expf(-__expf(td[ch]) * (float)CLEN);
  float s = 0.0f;
#pragma unroll
  for (int j = 0; j < NCH; ++j) {
    carry[(size_t)j * NCHAN + g] = s;
    s = dL * s + Sloc[(size_t)j * NCHAN + g];
  }
}

// pass C: replay with carry, add t=0 bonus, gate with sigmoid(r);
// rwkv may alias rr (in-place): rr[idx] is read before rwkv[idx] is written.
__global__ __launch_bounds__(256) void k_scan_c(
    const u16* __restrict__ kk, const u16* __restrict__ vv,
    const u16* __restrict__ rr, const float* __restrict__ td,
    const float* __restrict__ tf, const float* __restrict__ carry,
    u16* __restrict__ rwkv) {
  const int g = blockIdx.x * 256 + threadIdx.x;
  const int j = blockIdx.y;
  const int ch = g & (C_ - 1);
  const float d = __expf(-__expf(td[ch]));
  const float bonus = __expf(tf[ch]);
  const size_t base = ((size_t)(g >> 11) * T_ + (size_t)j * CLEN) * C_ + ch;
  float s = carry[(size_t)j * NCHAN + g];
#pragma unroll 2
  for (int t = 0; t < CLEN; ++t) {
    const size_t idx = base + (size_t)t * C_;
    const float vval = bf2f(vv[idx]);
    s = d * s + __expf(bf2f(kk[idx])) * vval;
    float wkv = s;
    if (j == 0 && t == 0) wkv += bonus * vval;
    const float rv = bf2f(rr[idx]);
    const float sg = 1.0f / (1.0f + __expf(-rv));
    rwkv[idx] = f2bf(sg * wkv);
  }
}

// ---------------- host launch ----------------
extern "C" void kernel_launch(void* const* d_in, const int* in_sizes, int n_in,
                              void* d_out, int out_size, void* d_ws, size_t ws_size,
                              hipStream_t stream) {
  const float* x    = (const float*)d_in[0];
  const float* td   = (const float*)d_in[1];
  const float* tf   = (const float*)d_in[2];
  const float* Wk   = (const float*)d_in[3];
  const float* Wv   = (const float*)d_in[4];
  const float* Wr   = (const float*)d_in[5];
  const float* Wo   = (const float*)d_in[6];
  const float* Wfk  = (const float*)d_in[7];
  const float* Wfv  = (const float*)d_in[8];
  const float* ln1w = (const float*)d_in[9];
  const float* ln1b = (const float*)d_in[10];
  const float* ln2w = (const float*)d_in[11];
  const float* ln2b = (const float*)d_in[12];
  float* out = (float*)d_out;

  // big path (z=4 shared-A FFN) needs ~193 MB; fallback (R11) needs 161 MB.
  const bool big = ws_size >= (size_t)203000000;

  char* p = (char*)d_ws;
  auto alloc = [&](size_t bytes) {
    char* r = p;
    p += (bytes + 255) & ~(size_t)255;
    return r;
  };
  u16*   wbuf = (u16*)alloc((size_t)4 * C_ * C_ * 2); // 32 MB: 4 transposed sq weights; later Wfk^T / Wfv^T chunks
  u16*   xl   = (u16*)alloc((size_t)M_ * C_ * 2);     // 32 MB: LN1 out; later hidden chunk 0
  u16*   kbuf = (u16*)alloc((size_t)M_ * C_ * 2);     // 32 MB: k; later hidden chunk 1
  u16*   vbuf = (u16*)alloc((size_t)M_ * C_ * 2);     // 32 MB: v; later xl2 (live through FFN)
  u16*   rbuf = (u16*)alloc((size_t)M_ * C_ * 2);     // 32 MB: r/rwkv; later hidden chunk 2
  u16*   h3   = big ? (u16*)alloc((size_t)M_ * C_ * 2) : nullptr; // 32 MB: hidden chunk 3 (big only)
  float* Sloc = (float*)alloc((size_t)NCH * NCHAN * 4);
  float* carry = (float*)alloc((size_t)NCH * NCHAN * 4);
  u16* rwkv = rbuf;
  u16* hchunk = xl;     // fallback: 64 MB spanning xl+kbuf (contiguous, both dead)
  u16* wfbuf = rbuf;    // fallback: 16 MB FFN chunk weight

  const dim3 ggrid(C_ / 256, M_ / 256);  // 8 x 32 = 256 blocks

  // 1) LN1
  k_layernorm_bf16<<<M_, 256, 0, stream>>>(x, ln1w, ln1b, xl);

  // 2) all 4 square weight transposes in one launch (z = Wk,Wv,Wr,Wo)
  k_transpose_cast4<<<dim3(C_ / 32, C_ / 32, 4), 256, 0, stream>>>(
      Wk, Wv, Wr, Wo, wbuf);

  // 3) k/v/r projections in one z=3 launch (shared-A; R11-measured 45.7% MfmaUtil)
  k_gemm8_kvr<<<dim3(C_ / 256, M_ / 256, 3), 512, 0, stream>>>(
      xl, wbuf, kbuf, vbuf, rbuf);

  // 4) wkv scan + gate
  k_scan_a<<<dim3(NCHAN / 256, NCH), 256, 0, stream>>>(kbuf, vbuf, td, Sloc);
  k_scan_b<<<dim3(NCHAN / 256), 256, 0, stream>>>(td, Sloc, carry);
  k_scan_c<<<dim3(NCHAN / 256, NCH), 256, 0, stream>>>(kbuf, vbuf, rbuf, td, tf, carry, rwkv);

  // 5) x2 = x + rwkv @ Wo -> d_out (Wo^T is wbuf slice 3)
  k_gemm8<1, false><<<ggrid, 512, 0, stream>>>(
      rwkv, nullptr, wbuf + (size_t)3 * C_ * C_, nullptr, out, x, M_, C_, C_);

  // 6) LN2 (xl2 into vbuf)
  u16* xl2 = vbuf;
  k_layernorm_bf16<<<M_, 256, 0, stream>>>(out, ln2w, ln2b, xl2);

  if (big) {
    // 7a) transpose all 4 Wfk N-chunks -> wbuf slices (wbuf dead after Wo)
    k_transpose_castZ<<<dim3(C_ / 32, C_ / 32, 4), 256, 0, stream>>>(
        Wfk, (size_t)C_, wbuf, (size_t)C_ * C_, C4_, C_, C_);
    // 8a) ONE z=4 shared-A Wfk GEMM -> hidden chunks in xl, kbuf, rbuf, h3
    k_gemm8_ffk4<<<dim3(C_ / 256, M_ / 256, 4), 512, 0, stream>>>(
        xl2, wbuf, xl, kbuf, rbuf, h3);
    // 9a) transpose all 4 Wfv K-chunks -> wbuf slices (Wfk^T dead now)
    k_transpose_castZ<<<dim3(C_ / 32, C_ / 32, 4), 256, 0, stream>>>(
        Wfv, (size_t)C_ * C_, wbuf, (size_t)C_ * C_, C_, C_, C_);
    // 10a) two stitched K=4096 Wfv GEMMs, EPI4 accumulate (sequential: no race)
    k_gemm8<4, true><<<ggrid, 512, 0, stream>>>(
        xl, kbuf, wbuf, wbuf + (size_t)C_ * C_, out, nullptr, M_, C_, C2_);
    k_gemm8<4, true><<<ggrid, 512, 0, stream>>>(
        rbuf, h3, wbuf + (size_t)2 * C_ * C_, wbuf + (size_t)3 * C_ * C_,
        out, nullptr, M_, C_, C2_);
  } else {
    // 7b) fallback: R11's 2-chunk FFN (proven at 161 MB arena)
    for (int c = 0; c < 2; ++c) {
      k_transpose_cast<<<dim3(C2_ / 32, C_ / 32), 256, 0, stream>>>(
          Wfk + (size_t)c * C2_, wfbuf, C4_, C_, C2_);
      k_gemm8<3, false><<<dim3(C2_ / 256, M_ / 256), 512, 0, stream>>>(
          xl2, nullptr, wfbuf, nullptr, hchunk, nullptr, M_, C2_, C_);
      k_transpose_cast<<<dim3(C_ / 32, C2_ / 32), 256, 0, stream>>>(
          Wfv + (size_t)c * C2_ * C_, wfbuf, C_, C2_, C_);
      k_gemm8<4, false><<<dim3(C_ / 256, M_ / 256), 512, 0, stream>>>(
          hchunk, nullptr, wfbuf, nullptr, out, nullptr, M_, C_, C2_);
    }
  }
}

// Round 13
// 958.027 us; speedup vs baseline: 1.0320x; 1.0320x over previous
//
#include <hip/hip_runtime.h>
#include <hip/hip_bf16.h>
#include <stdint.h>

#define B_  4
#define T_  2048
#define C_  2048
#define H_  32
#define S_  64
#define M_  (B_ * T_)     // 8192 rows
#define C4_ (4 * C_)      // 8192
#define C2_ (2 * C_)      // 4096
#define LN_EPS 1e-5f
#define NCH 16            // scan chunks
#define CLEN 128          // chunk length (NCH*CLEN == T_)
#define NCHAN (B_ * C_)   // 8192 scan channels

typedef unsigned short u16;
typedef __attribute__((ext_vector_type(8))) short short8;
typedef __attribute__((ext_vector_type(4))) float f32x4;

__device__ __forceinline__ u16 f2bf(float f) {
  uint32_t u = __float_as_uint(f);
  u = (u + 0x7FFFu + ((u >> 16) & 1u)) >> 16;
  return (u16)u;
}
__device__ __forceinline__ float bf2f(u16 u) {
  return __uint_as_float(((uint32_t)u) << 16);
}

__device__ __forceinline__ void gload_lds16(const void* g, void* l) {
  __builtin_amdgcn_global_load_lds(
      (const __attribute__((address_space(1))) uint32_t*)g,
      (__attribute__((address_space(3))) uint32_t*)l, 16, 0, 0);
}

// ---- transpose + cast: f32 in[R][Cn] (leading dim ld) -> bf16 out[Cn][R] ----
__global__ __launch_bounds__(256) void k_transpose_cast(
    const float* __restrict__ in, u16* __restrict__ out, int ld, int R, int Cn) {
  __shared__ float tile[32][33];
  const int tx = threadIdx.x & 31, ty = threadIdx.x >> 5; // ty 0..7
  const int c0 = blockIdx.x * 32, r0 = blockIdx.y * 32;
#pragma unroll
  for (int i = 0; i < 4; ++i) {
    int r = ty + i * 8;
    tile[r][tx] = in[(size_t)(r0 + r) * ld + (c0 + tx)];
  }
  __syncthreads();
#pragma unroll
  for (int i = 0; i < 4; ++i) {
    int cc = ty + i * 8;
    out[(size_t)(c0 + cc) * R + (r0 + tx)] = f2bf(tile[tx][cc]);
  }
}

// ---- z-batched chunk transpose: in = in0 + z*in_zoff, out = out0 + z*out_zoff ----
__global__ __launch_bounds__(256) void k_transpose_castZ(
    const float* __restrict__ in0, size_t in_zoff,
    u16* __restrict__ out0, size_t out_zoff, int ld, int R, int Cn) {
  __shared__ float tile[32][33];
  const float* in = in0 + in_zoff * blockIdx.z;
  u16* out = out0 + out_zoff * blockIdx.z;
  const int tx = threadIdx.x & 31, ty = threadIdx.x >> 5;
  const int c0 = blockIdx.x * 32, r0 = blockIdx.y * 32;
#pragma unroll
  for (int i = 0; i < 4; ++i) {
    int r = ty + i * 8;
    tile[r][tx] = in[(size_t)(r0 + r) * ld + (c0 + tx)];
  }
  __syncthreads();
#pragma unroll
  for (int i = 0; i < 4; ++i) {
    int cc = ty + i * 8;
    out[(size_t)(c0 + cc) * R + (r0 + tx)] = f2bf(tile[tx][cc]);
  }
}

// ---- batched square transpose: z selects one of 4 C_xC_ weights -> wbuf slice z ----
__global__ __launch_bounds__(256) void k_transpose_cast4(
    const float* __restrict__ w0, const float* __restrict__ w1,
    const float* __restrict__ w2, const float* __restrict__ w3,
    u16* __restrict__ out) {
  __shared__ float tile[32][33];
  const float* in = blockIdx.z == 0 ? w0 : blockIdx.z == 1 ? w1
                  : blockIdx.z == 2 ? w2 : w3;
  u16* o = out + (size_t)blockIdx.z * C_ * C_;
  const int tx = threadIdx.x & 31, ty = threadIdx.x >> 5;
  const int c0 = blockIdx.x * 32, r0 = blockIdx.y * 32;
#pragma unroll
  for (int i = 0; i < 4; ++i) {
    int r = ty + i * 8;
    tile[r][tx] = in[(size_t)(r0 + r) * C_ + (c0 + tx)];
  }
  __syncthreads();
#pragma unroll
  for (int i = 0; i < 4; ++i) {
    int cc = ty + i * 8;
    o[(size_t)(c0 + cc) * C_ + (r0 + tx)] = f2bf(tile[tx][cc]);
  }
}

// ---------------- LayerNorm f32 -> bf16, one block per row ----------------
__global__ __launch_bounds__(256) void k_layernorm_bf16(
    const float* __restrict__ x, const float* __restrict__ w,
    const float* __restrict__ bias, u16* __restrict__ out) {
  const int row = blockIdx.x;
  const int t = threadIdx.x;
  const float* xr = x + (size_t)row * C_;
  float4 a = ((const float4*)xr)[2 * t];
  float4 b = ((const float4*)xr)[2 * t + 1];
  float s = a.x + a.y + a.z + a.w + b.x + b.y + b.z + b.w;
  float q = a.x * a.x + a.y * a.y + a.z * a.z + a.w * a.w +
            b.x * b.x + b.y * b.y + b.z * b.z + b.w * b.w;
#pragma unroll
  for (int off = 32; off > 0; off >>= 1) {
    s += __shfl_down(s, off);
    q += __shfl_down(q, off);
  }
  __shared__ float rs[8];
  const int wv = t >> 6;
  if ((t & 63) == 0) { rs[wv] = s; rs[4 + wv] = q; }
  __syncthreads();
  s = rs[0] + rs[1] + rs[2] + rs[3];
  q = rs[4] + rs[5] + rs[6] + rs[7];
  const float mean = s * (1.0f / C_);
  const float rstd = rsqrtf(q * (1.0f / C_) - mean * mean + LN_EPS);
  float4 w0 = ((const float4*)w)[2 * t], w1 = ((const float4*)w)[2 * t + 1];
  float4 b0 = ((const float4*)bias)[2 * t], b1 = ((const float4*)bias)[2 * t + 1];
  uint4 pk;
  pk.x = (uint32_t)f2bf((a.x - mean) * rstd * w0.x + b0.x) |
         ((uint32_t)f2bf((a.y - mean) * rstd * w0.y + b0.y) << 16);
  pk.y = (uint32_t)f2bf((a.z - mean) * rstd * w0.z + b0.z) |
         ((uint32_t)f2bf((a.w - mean) * rstd * w0.w + b0.w) << 16);
  pk.z = (uint32_t)f2bf((b.x - mean) * rstd * w1.x + b1.x) |
         ((uint32_t)f2bf((b.y - mean) * rstd * w1.y + b1.y) << 16);
  pk.w = (uint32_t)f2bf((b.z - mean) * rstd * w1.z + b1.z) |
         ((uint32_t)f2bf((b.w - mean) * rstd * w1.w + b1.w) << 16);
  ((uint4*)(out + (size_t)row * C_))[t] = pk;
}

// ====== GEMM 256x256, BK=64, 8 waves, sparse barriers + counted vmcnt (R5, proven) ======
// Branch-free staging only (R12 lesson: a runtime kcol branch in the staging
// path cost ~+18% on the stitched GEMMs — keep K-loop address math straight).
__device__ __forceinline__ void stage_half(
    const u16* __restrict__ G, int ldK, int row0, int kcol0,
    u16* lds_half, int tid) {
#pragma unroll
  for (int i = 0; i < 2; ++i) {
    const int slot = i * 512 + tid;
    const int row = slot >> 2;
    const int gs = slot & 3;
    const int gsrc = gs ^ ((row >> 1) & 3);
    gload_lds16(G + (size_t)(row0 + row) * ldK + kcol0 + gsrc * 8,
                ((char*)lds_half) + i * 8192 + (tid >> 6) * 1024);
  }
}

__device__ __forceinline__ short8 frag(const u16* half_base, int row, int g0) {
  const int g = g0 ^ ((row >> 1) & 3);
  return *(const short8*)(half_base + row * 32 + g * 8);
}

template <typename ACC>
__device__ __forceinline__ void gemm_body(
    const u16* __restrict__ A, const u16* __restrict__ Bt,
    int K, int bm0, int bn0, int tid, ACC& acc,
    u16 (*As)[2][256 * 32], u16 (*Bs)[2][256 * 32]) {
  const int wv = tid >> 6, ln = tid & 63;
  const int wm = wv >> 2, wn = wv & 3;
  const int l15 = ln & 15, g0 = ln >> 4;
  const int NT = K >> 6;

  stage_half(A, K, bm0, 0, &As[0][0][0], tid);
  stage_half(Bt, K, bn0, 0, &Bs[0][0][0], tid);
  stage_half(A, K, bm0, 32, &As[0][1][0], tid);
  stage_half(Bt, K, bn0, 32, &Bs[0][1][0], tid);
  asm volatile("s_waitcnt vmcnt(4)" ::: "memory");
  __builtin_amdgcn_s_barrier();
  __builtin_amdgcn_sched_barrier(0);

  for (int t = 0; t < NT; ++t) {
    const int c = t & 1, nb = c ^ 1;
    const int kn = (t + 1) << 6;
    const bool stage_on = (t + 1 < NT);
    const bool lastt = (t + 1 == NT);
    short8 bfr[4], af[4];

#pragma unroll
    for (int h = 0; h < 2; ++h) {
#pragma unroll
      for (int n = 0; n < 4; ++n)
        bfr[n] = frag(&Bs[c][h][0], wn * 64 + n * 16 + l15, g0);
#pragma unroll
      for (int m = 0; m < 4; ++m)
        af[m] = frag(&As[c][h][0], wm * 128 + m * 16 + l15, g0);
      if (stage_on) stage_half(A, K, bm0, kn + h * 32, &As[nb][h][0], tid);
#pragma unroll
      for (int m = 0; m < 4; ++m)
#pragma unroll
        for (int n = 0; n < 4; ++n)
          acc[m][n] = __builtin_amdgcn_mfma_f32_16x16x32_bf16(af[m], bfr[n], acc[m][n], 0, 0, 0);

#pragma unroll
      for (int m = 0; m < 4; ++m)
        af[m] = frag(&As[c][h][0], wm * 128 + 64 + m * 16 + l15, g0);
      if (stage_on) stage_half(Bt, K, bn0, kn + h * 32, &Bs[nb][h][0], tid);
#pragma unroll
      for (int m = 0; m < 4; ++m)
#pragma unroll
        for (int n = 0; n < 4; ++n)
          acc[4 + m][n] = __builtin_amdgcn_mfma_f32_16x16x32_bf16(af[m], bfr[n], acc[4 + m][n], 0, 0, 0);

      if (h == 0) {
        if (!lastt) asm volatile("s_waitcnt vmcnt(4)" ::: "memory");  // t.K1 landed
        else        asm volatile("s_waitcnt vmcnt(0)" ::: "memory");
        __builtin_amdgcn_s_barrier();
        __builtin_amdgcn_sched_barrier(0);
      } else if (!lastt) {
        asm volatile("s_waitcnt vmcnt(4)" ::: "memory");              // (t+1).K0 landed
        __builtin_amdgcn_s_barrier();
        __builtin_amdgcn_sched_barrier(0);
      }
    }
  }
}

// XCD-aware remap (T1): bijective since nwg % 8 == 0 for all grids here.
__device__ __forceinline__ void xcd_remap(int& bm0, int& bn0) {
  const int lin = blockIdx.y * gridDim.x + blockIdx.x;
  const int xcd = lin & 7, slot = lin >> 3;
  const int bx = slot % gridDim.x;
  const int by = xcd * (gridDim.y >> 3) + slot / gridDim.x;
  bm0 = by * 256; bn0 = bx * 256;
}

// EPI: 0 f32 | 1 f32 Res+v | 2 bf16 | 3 bf16 relu^2 | 4 f32 +=
template <int EPI>
__global__ __launch_bounds__(512, 2) void k_gemm8(
    const u16* __restrict__ A, const u16* __restrict__ Bt,
    void* __restrict__ Out, const float* __restrict__ Res,
    int M, int N, int K) {
  __shared__ u16 As[2][2][256 * 32];
  __shared__ u16 Bs[2][2][256 * 32];
  const int tid = threadIdx.x;
  const int wv = tid >> 6, ln = tid & 63;
  const int wm = wv >> 2, wn = wv & 3;
  const int l15 = ln & 15;
  int bm0, bn0;
  xcd_remap(bm0, bn0);

  f32x4 acc[8][4];
#pragma unroll
  for (int m = 0; m < 8; ++m)
#pragma unroll
    for (int n = 0; n < 4; ++n) acc[m][n] = (f32x4)0.0f;

  gemm_body(A, Bt, K, bm0, bn0, tid, acc, As, Bs);

#pragma unroll
  for (int m = 0; m < 8; ++m) {
    const int r_base = bm0 + wm * 128 + m * 16 + (ln >> 4) * 4;
#pragma unroll
    for (int n = 0; n < 4; ++n) {
      const int cidx = bn0 + wn * 64 + n * 16 + l15;
#pragma unroll
      for (int i = 0; i < 4; ++i) {
        const size_t off = (size_t)(r_base + i) * N + cidx;
        const float v = acc[m][n][i];
        if constexpr (EPI == 0) {
          ((float*)Out)[off] = v;
        } else if constexpr (EPI == 1) {
          ((float*)Out)[off] = Res[off] + v;
        } else if constexpr (EPI == 2) {
          ((u16*)Out)[off] = f2bf(v);
        } else if constexpr (EPI == 3) {
          const float tpos = v > 0.0f ? v : 0.0f;
          ((u16*)Out)[off] = f2bf(tpos * tpos);
        } else {
          ((float*)Out)[off] += v;
        }
      }
    }
  }
}

// k/v/r fused: z selects weight slice (Wt + z*C*C) and output buffer; bf16 out.
// Shared A across z -> A staging panels L2-hit for z>=1 (measured 45.7% MfmaUtil).
__global__ __launch_bounds__(512, 2) void k_gemm8_kvr(
    const u16* __restrict__ A, const u16* __restrict__ Wt,
    u16* __restrict__ kb, u16* __restrict__ vb, u16* __restrict__ rb) {
  __shared__ u16 As[2][2][256 * 32];
  __shared__ u16 Bs[2][2][256 * 32];
  const int tid = threadIdx.x;
  const int wv = tid >> 6, ln = tid & 63;
  const int wm = wv >> 2, wn = wv & 3;
  const int l15 = ln & 15;
  const u16* Bt = Wt + (size_t)blockIdx.z * C_ * C_;
  u16* Out = blockIdx.z == 0 ? kb : blockIdx.z == 1 ? vb : rb;
  int bm0, bn0;
  xcd_remap(bm0, bn0);

  f32x4 acc[8][4];
#pragma unroll
  for (int m = 0; m < 8; ++m)
#pragma unroll
    for (int n = 0; n < 4; ++n) acc[m][n] = (f32x4)0.0f;

  gemm_body(A, Bt, C_, bm0, bn0, tid, acc, As, Bs);

#pragma unroll
  for (int m = 0; m < 8; ++m) {
    const int r_base = bm0 + wm * 128 + m * 16 + (ln >> 4) * 4;
#pragma unroll
    for (int n = 0; n < 4; ++n) {
      const int cidx = bn0 + wn * 64 + n * 16 + l15;
#pragma unroll
      for (int i = 0; i < 4; ++i)
        Out[(size_t)(r_base + i) * C_ + cidx] = f2bf(acc[m][n][i]);
    }
  }
}

// z=4 shared-A FFN-Wfk GEMM: hidden cols [z*2048,(z+1)*2048) of ONE contiguous
// [M][8192] buffer = relu(xl2 @ WfkT_z)^2. Shared-A L2 mechanism (46% MfmaUtil,
// R12-measured); contiguous ld=C4_ output enables the single K=8192 Wfv GEMM.
__global__ __launch_bounds__(512, 2) void k_gemm8_ffk4(
    const u16* __restrict__ A, const u16* __restrict__ Wt,
    u16* __restrict__ H) {
  __shared__ u16 As[2][2][256 * 32];
  __shared__ u16 Bs[2][2][256 * 32];
  const int tid = threadIdx.x;
  const int wv = tid >> 6, ln = tid & 63;
  const int wm = wv >> 2, wn = wv & 3;
  const int l15 = ln & 15;
  const u16* Bt = Wt + (size_t)blockIdx.z * C_ * C_;
  u16* Out = H + (size_t)blockIdx.z * C_;   // column block z, ld = C4_
  int bm0, bn0;
  xcd_remap(bm0, bn0);

  f32x4 acc[8][4];
#pragma unroll
  for (int m = 0; m < 8; ++m)
#pragma unroll
    for (int n = 0; n < 4; ++n) acc[m][n] = (f32x4)0.0f;

  gemm_body(A, Bt, C_, bm0, bn0, tid, acc, As, Bs);

#pragma unroll
  for (int m = 0; m < 8; ++m) {
    const int r_base = bm0 + wm * 128 + m * 16 + (ln >> 4) * 4;
#pragma unroll
    for (int n = 0; n < 4; ++n) {
      const int cidx = bn0 + wn * 64 + n * 16 + l15;
#pragma unroll
      for (int i = 0; i < 4; ++i) {
        const float v = acc[m][n][i];
        const float tpos = v > 0.0f ? v : 0.0f;
        Out[(size_t)(r_base + i) * C4_ + cidx] = f2bf(tpos * tpos);
      }
    }
  }
}

// ---------------- wkv scan, 3 passes (chunked exp-decay cumsum) ----------------
__global__ __launch_bounds__(256) void k_scan_a(
    const u16* __restrict__ kk, const u16* __restrict__ vv,
    const float* __restrict__ td, float* __restrict__ Sloc) {
  const int g = blockIdx.x * 256 + threadIdx.x;
  const int j = blockIdx.y;
  const int ch = g & (C_ - 1);
  const float d = __expf(-__expf(td[ch]));
  const size_t base = ((size_t)(g >> 11) * T_ + (size_t)j * CLEN) * C_ + ch;
  float s = 0.0f;
#pragma unroll 4
  for (int t = 0; t < CLEN; ++t) {
    const size_t idx = base + (size_t)t * C_;
    s = d * s + __expf(bf2f(kk[idx])) * bf2f(vv[idx]);
  }
  Sloc[(size_t)j * NCHAN + g] = s;
}

__global__ __launch_bounds__(256) void k_scan_b(
    const float* __restrict__ td, const float* __restrict__ Sloc,
    float* __restrict__ carry) {
  const int g = blockIdx.x * 256 + threadIdx.x;
  const int ch = g & (C_ - 1);
  const float dL = __expf(-__expf(td[ch]) * (float)CLEN);
  float s = 0.0f;
#pragma unroll
  for (int j = 0; j < NCH; ++j) {
    carry[(size_t)j * NCHAN + g] = s;
    s = dL * s + Sloc[(size_t)j * NCHAN + g];
  }
}

// pass C: replay with carry, add t=0 bonus, gate with sigmoid(r);
// rwkv may alias rr (in-place): rr[idx] is read before rwkv[idx] is written.
__global__ __launch_bounds__(256) void k_scan_c(
    const u16* __restrict__ kk, const u16* __restrict__ vv,
    const u16* __restrict__ rr, const float* __restrict__ td,
    const float* __restrict__ tf, const float* __restrict__ carry,
    u16* __restrict__ rwkv) {
  const int g = blockIdx.x * 256 + threadIdx.x;
  const int j = blockIdx.y;
  const int ch = g & (C_ - 1);
  const float d = __expf(-__expf(td[ch]));
  const float bonus = __expf(tf[ch]);
  const size_t base = ((size_t)(g >> 11) * T_ + (size_t)j * CLEN) * C_ + ch;
  float s = carry[(size_t)j * NCHAN + g];
#pragma unroll 2
  for (int t = 0; t < CLEN; ++t) {
    const size_t idx = base + (size_t)t * C_;
    const float vval = bf2f(vv[idx]);
    s = d * s + __expf(bf2f(kk[idx])) * vval;
    float wkv = s;
    if (j == 0 && t == 0) wkv += bonus * vval;
    const float rv = bf2f(rr[idx]);
    const float sg = 1.0f / (1.0f + __expf(-rv));
    rwkv[idx] = f2bf(sg * wkv);
  }
}

// ---------------- host launch ----------------
extern "C" void kernel_launch(void* const* d_in, const int* in_sizes, int n_in,
                              void* d_out, int out_size, void* d_ws, size_t ws_size,
                              hipStream_t stream) {
  const float* x    = (const float*)d_in[0];
  const float* td   = (const float*)d_in[1];
  const float* tf   = (const float*)d_in[2];
  const float* Wk   = (const float*)d_in[3];
  const float* Wv   = (const float*)d_in[4];
  const float* Wr   = (const float*)d_in[5];
  const float* Wo   = (const float*)d_in[6];
  const float* Wfk  = (const float*)d_in[7];
  const float* Wfv  = (const float*)d_in[8];
  const float* ln1w = (const float*)d_in[9];
  const float* ln1b = (const float*)d_in[10];
  const float* ln2w = (const float*)d_in[11];
  const float* ln2b = (const float*)d_in[12];
  float* out = (float*)d_out;

  // big path needs ~193 MB (contiguous 128 MB hidden); fallback needs 161 MB.
  const bool big = ws_size >= (size_t)203000000;

  // Arena order is load-bearing in the big path: xl,kbuf,rbuf,h3 are four
  // consecutive 32 MB (256-aligned, no padding) blocks = ONE contiguous
  // [M][C4_] hidden buffer for the FFN.
  char* p = (char*)d_ws;
  auto alloc = [&](size_t bytes) {
    char* r = p;
    p += (bytes + 255) & ~(size_t)255;
    return r;
  };
  u16*   wbuf = (u16*)alloc((size_t)4 * C_ * C_ * 2); // 32 MB: sq weights; later WfkT/WfvT
  u16*   xl   = (u16*)alloc((size_t)M_ * C_ * 2);     // 32 MB: LN1 out; hidden cols 0-2047
  u16*   kbuf = (u16*)alloc((size_t)M_ * C_ * 2);     // 32 MB: k; hidden cols 2048-4095
  u16*   rbuf = (u16*)alloc((size_t)M_ * C_ * 2);     // 32 MB: r/rwkv; hidden cols 4096-6143
  u16*   h3   = big ? (u16*)alloc((size_t)M_ * C_ * 2) : nullptr; // 32 MB: hidden cols 6144-8191
  u16*   vbuf = (u16*)alloc((size_t)M_ * C_ * 2);     // 32 MB: v; later xl2 (live thru FFN)
  float* Sloc = (float*)alloc((size_t)NCH * NCHAN * 4);
  float* carry = (float*)alloc((size_t)NCH * NCHAN * 4);
  u16* rwkv = rbuf;     // alias: in-place gate (read-before-write per element)
  u16* hidden = xl;     // big: [M][C4_] spanning xl..h3
  u16* hchunk = xl;     // fallback: 64 MB spanning xl+kbuf
  u16* wfbuf = rbuf;    // fallback: 16 MB FFN chunk weight

  const dim3 ggrid(C_ / 256, M_ / 256);  // 8 x 32 = 256 blocks

  // 1) LN1
  k_layernorm_bf16<<<M_, 256, 0, stream>>>(x, ln1w, ln1b, xl);

  // 2) all 4 square weight transposes in one launch (z = Wk,Wv,Wr,Wo)
  k_transpose_cast4<<<dim3(C_ / 32, C_ / 32, 4), 256, 0, stream>>>(
      Wk, Wv, Wr, Wo, wbuf);

  // 3) k/v/r projections in one z=3 shared-A launch
  k_gemm8_kvr<<<dim3(C_ / 256, M_ / 256, 3), 512, 0, stream>>>(
      xl, wbuf, kbuf, vbuf, rbuf);

  // 4) wkv scan + gate
  k_scan_a<<<dim3(NCHAN / 256, NCH), 256, 0, stream>>>(kbuf, vbuf, td, Sloc);
  k_scan_b<<<dim3(NCHAN / 256), 256, 0, stream>>>(td, Sloc, carry);
  k_scan_c<<<dim3(NCHAN / 256, NCH), 256, 0, stream>>>(kbuf, vbuf, rbuf, td, tf, carry, rwkv);

  // 5) x2 = x + rwkv @ Wo -> d_out (Wo^T is wbuf slice 3)
  k_gemm8<1><<<ggrid, 512, 0, stream>>>(
      rwkv, wbuf + (size_t)3 * C_ * C_, out, x, M_, C_, C_);

  // 6) LN2 (xl2 into vbuf)
  u16* xl2 = vbuf;
  k_layernorm_bf16<<<M_, 256, 0, stream>>>(out, ln2w, ln2b, xl2);

  if (big) {
    // 7a) transpose all 4 Wfk N-chunks -> wbuf slices (wbuf dead after Wo)
    k_transpose_castZ<<<dim3(C_ / 32, C_ / 32, 4), 256, 0, stream>>>(
        Wfk, (size_t)C_, wbuf, (size_t)C_ * C_, C4_, C_, C_);
    // 8a) ONE z=4 shared-A Wfk GEMM -> contiguous [M][C4_] hidden
    k_gemm8_ffk4<<<dim3(C_ / 256, M_ / 256, 4), 512, 0, stream>>>(
        xl2, wbuf, hidden);
    // 9a) transpose full Wfv [C4_][C_] -> [C_][C4_] into wbuf (32 MB)
    k_transpose_cast<<<dim3(C_ / 32, C4_ / 32), 256, 0, stream>>>(
        Wfv, wbuf, C_, C4_, C_);
    // 10a) ONE K=8192 Wfv GEMM: out += hidden @ Wfv  (branch-free staging)
    k_gemm8<4><<<ggrid, 512, 0, stream>>>(
        hidden, wbuf, out, nullptr, M_, C_, C4_);
  } else {
    // 7b) fallback: R11's 2-chunk FFN (proven at 161 MB arena)
    for (int c = 0; c < 2; ++c) {
      k_transpose_cast<<<dim3(C2_ / 32, C_ / 32), 256, 0, stream>>>(
          Wfk + (size_t)c * C2_, wfbuf, C4_, C_, C2_);
      k_gemm8<3><<<dim3(C2_ / 256, M_ / 256), 512, 0, stream>>>(
          xl2, wfbuf, hchunk, nullptr, M_, C2_, C_);
      k_transpose_cast<<<dim3(C_ / 32, C2_ / 32), 256, 0, stream>>>(
          Wfv + (size_t)c * C2_ * C_, wfbuf, C_, C2_, C_);
      k_gemm8<4><<<dim3(C_ / 256, M_ / 256), 512, 0, stream>>>(
          hchunk, wfbuf, out, nullptr, M_, C_, C2_);
    }
  }
}